// Round 11
// baseline (210.420 us; speedup 1.0000x reference)
//
#include <hip/hip_runtime.h>

// Problem constants
#define BATCH 2
#define SLEN 2048
#define DMODEL 1024
#define NHEAD 16
#define HDIM 64
#define MROWS (BATCH * SLEN)   // 4096

typedef __attribute__((ext_vector_type(8))) short bf16x8;
typedef __attribute__((ext_vector_type(4))) short bf16x4;
typedef __attribute__((ext_vector_type(4))) float f32x4;
typedef __attribute__((ext_vector_type(8))) _Float16 f16x8;
typedef __attribute__((ext_vector_type(4))) _Float16 f16x4;

__device__ inline short f2bf(float x) {
    union { float f; unsigned u; } v; v.f = x;
    unsigned r = (v.u + 0x7FFFu + ((v.u >> 16) & 1u)) >> 16;
    return (short)r;
}
__device__ inline float bf2f(short h) {
    union { unsigned u; float f; } v; v.u = ((unsigned)(unsigned short)h) << 16;
    return v.f;
}
__device__ inline unsigned fbits(float x) {
    union { float f; unsigned u; } v; v.f = x; return v.u;
}
// raw hardware exp2: one v_exp_f32 (args bounded; no denormal fixup needed)
__device__ inline float hw_exp2(float x) {
    float r;
    asm("v_exp_f32 %0, %1" : "=v"(r) : "v"(x));
    return r;
}

// ---------------- fused prep: cast x -> fp16  +  transpose both weight
// matrices to fp16 [N][K]. One launch instead of three.
#define NCAST (MROWS * DMODEL / 4 / 256)                    // 4096 blocks
#define NTW1  ((3 * DMODEL / 64) * (DMODEL / 64))           // 48*16 = 768
#define NTW2  ((DMODEL / 64) * (DMODEL / 64))               // 16*16 = 256

__global__ __launch_bounds__(256) void prep(
    const float* __restrict__ x, _Float16* __restrict__ xf,
    const float* __restrict__ Wqkv, _Float16* __restrict__ wq,
    const float* __restrict__ Wproj, _Float16* __restrict__ wp)
{
    __shared__ float T[64][68];
    int bid = blockIdx.x;
    const int tid = threadIdx.x;

    if (bid < NCAST) {            // ---- cast x (uniform per block; no barrier)
        int i = bid * 256 + tid;
        float4 f = ((const float4*)x)[i];
        f16x4 h;
        h[0] = (_Float16)f.x; h[1] = (_Float16)f.y;
        h[2] = (_Float16)f.z; h[3] = (_Float16)f.w;
        ((f16x4*)xf)[i] = h;
        return;
    }
    bid -= NCAST;

    const float* in; _Float16* outT; int N; int n0, k0;
    if (bid < NTW1) {             // ---- transpose W_qkv [1024][3072]
        in = Wqkv; outT = wq; N = 3 * DMODEL;
        n0 = (bid % 48) * 64; k0 = (bid / 48) * 64;
    } else {                      // ---- transpose W_proj [1024][1024]
        bid -= NTW1;
        in = Wproj; outT = wp; N = DMODEL;
        n0 = (bid % 16) * 64; k0 = (bid / 16) * 64;
    }
    const int K = DMODEL;

#pragma unroll
    for (int i = 0; i < 4; i++) {
        int idx = tid + i * 256;
        int r = idx >> 4, c4 = idx & 15;
        *(float4*)&T[r][c4 * 4] = *(const float4*)&in[(size_t)(k0 + r) * N + n0 + c4 * 4];
    }
    __syncthreads();
#pragma unroll
    for (int i = 0; i < 4; i++) {
        int idx = tid + i * 256;
        int n = idx >> 4, kg = idx & 15;
        f16x4 h;
#pragma unroll
        for (int j = 0; j < 4; j++)
            h[j] = (_Float16)T[kg * 4 + j][n];
        *(f16x4*)&outT[(size_t)(n0 + n) * K + k0 + kg * 4] = h;
    }
}

// ---------------- transpose V section of qkv -> vT[b][h][d][s]  (bf16)
__global__ __launch_bounds__(256) void transpose_v(
    const short* __restrict__ qkv, short* __restrict__ vT)
{
    __shared__ short T[64 * 68];   // [s][d], stride 68 shorts
    const int tid = threadIdx.x;
    const int bid = blockIdx.x;
    const int st = bid & 31, h = (bid >> 5) & 15, b = bid >> 9;
    const int s0 = st * 64;
    const short* src = qkv + (size_t)b * SLEN * (3 * DMODEL) + 2 * DMODEL + h * HDIM;

    const int srow = tid >> 3, sc8 = tid & 7;
#pragma unroll
    for (int it = 0; it < 2; it++) {
        int s = srow + it * 32;
        *(bf16x8*)&T[s * 68 + sc8 * 8] =
            *(const bf16x8*)&src[(size_t)(s0 + s) * (3 * DMODEL) + sc8 * 8];
    }
    __syncthreads();

    const int d = tid >> 2, sq = tid & 3;
    short* dst = vT + ((size_t)(b * NHEAD + h) * HDIM + d) * SLEN + s0 + sq * 16;
    bf16x8 o0, o1;
#pragma unroll
    for (int j = 0; j < 8; j++) {
        o0[j] = T[(sq * 16 + j) * 68 + d];
        o1[j] = T[(sq * 16 + 8 + j) * 68 + d];
    }
    *(bf16x8*)&dst[0] = o0;
    *(bf16x8*)&dst[8] = o1;
}

// ---------------- plain fp16 MFMA GEMM: C = A[M,K] · B[K,N] + bias
// B given TRANSPOSED [N][K] fp16. 128x128 tiles, BK=64.
// v18: global_load_lds staging (m151: +35% vs reg-staging on this structure).
// LDS is LINEAR [128][64] f16 (global_load_lds demands wave-uniform base +
// lane*16 dest); bank conflicts on the 128B-row reads are fixed by the
// both-sides XOR swizzle (rule #21): global SOURCE col-group pre-swizzled
// (scl ^ srl) — still one 128B segment per 8 lanes — and the ds_read col
// XORs (lr&7). Read bank-starts {0,4..28} per 8 lanes -> free 2-way.
#define BK 64

template<int OUT_BF16>
__global__ __launch_bounds__(256) void gemm_f16(
    const _Float16* __restrict__ A, const _Float16* __restrict__ Bw,
    const float* __restrict__ bias, void* __restrict__ Cout,
    int M, int N, int K)
{
    __shared__ _Float16 As[128 * BK], Bs[128 * BK];

    const int tid  = threadIdx.x;
    const int wave = tid >> 6, lane = tid & 63;
    const int quad = lane >> 4, lr = lane & 15;
    const int wm = (wave >> 1) * 64, wn = (wave & 1) * 64;
    const int row0 = blockIdx.y * 128, col0 = blockIdx.x * 128;

    f32x4 acc[4][4];
#pragma unroll
    for (int i = 0; i < 4; i++)
#pragma unroll
        for (int j = 0; j < 4; j++) acc[i][j] = (f32x4){0.f, 0.f, 0.f, 0.f};

    // staging geometry: per issue, wave covers 8 rows x 64 cols (1 KB).
    const int srl = lane >> 3;              // row within wave's octet (0..7)
    const int scl = lane & 7;               // physical col-group this lane fills
    const int swz = scl ^ srl;              // logical col-group to FETCH (inverse swizzle)

    for (int k0 = 0; k0 < K; k0 += BK) {
        __syncthreads();   // prev tile's reads done; LDS reusable
#pragma unroll
        for (int i = 0; i < 4; i++) {
            const int rbase = i * 32 + wave * 8;
            const int r = rbase + srl;
            __builtin_amdgcn_global_load_lds(
                (const __attribute__((address_space(1))) unsigned int*)
                    &A[(size_t)(row0 + r) * K + k0 + swz * 8],
                (__attribute__((address_space(3))) unsigned int*)&As[rbase * BK],
                16, 0, 0);
            __builtin_amdgcn_global_load_lds(
                (const __attribute__((address_space(1))) unsigned int*)
                    &Bw[(size_t)(col0 + r) * K + k0 + swz * 8],
                (__attribute__((address_space(3))) unsigned int*)&Bs[rbase * BK],
                16, 0, 0);
        }
        __syncthreads();   // compiler drains vmcnt(0) before this barrier

#pragma unroll
        for (int kk = 0; kk < 2; kk++) {
            const int cb = ((kk * 4 + quad) ^ (lr & 7)) * 8;   // swizzled col (shorts)
            f16x8 af[4];
#pragma unroll
            for (int mt = 0; mt < 4; mt++)
                af[mt] = *(const f16x8*)&As[(wm + mt * 16 + lr) * BK + cb];
#pragma unroll
            for (int nt = 0; nt < 4; nt++) {
                f16x8 b = *(const f16x8*)&Bs[(wn + nt * 16 + lr) * BK + cb];
#pragma unroll
                for (int mt = 0; mt < 4; mt++)
                    acc[mt][nt] = __builtin_amdgcn_mfma_f32_16x16x32_f16(af[mt], b, acc[mt][nt], 0, 0, 0);
            }
        }
    }

    // epilogue: D[m = quad*4 + r][n = lr]
#pragma unroll
    for (int mt = 0; mt < 4; mt++) {
#pragma unroll
        for (int nt = 0; nt < 4; nt++) {
            int col = col0 + wn + nt * 16 + lr;
            float bv = bias[col];
#pragma unroll
            for (int r = 0; r < 4; r++) {
                int row = row0 + wm + mt * 16 + quad * 4 + r;
                float v = acc[mt][nt][r] + bv;
                if (OUT_BF16)
                    ((short*)Cout)[(size_t)row * N + col] = f2bf(v);
                else
                    ((float*)Cout)[(size_t)row * N + col] = v;
            }
        }
    }
}

// ---------------- fused attention v16 (verified 65.5 µs; round-10's 69.6 on
// identical code = noise/interference): q/ct split per wave + pair-reduce
// epilogue. NOTE: plain __launch_bounds__(256) — the (256,4) min-occupancy
// cap produced silently-wrong spill codegen twice (v10, v15). Keep plain.
#define ASTR 72   // LDS row stride (shorts): 144 B, 16B-aligned rows
#define NT   (SLEN / 64)
#define RSTR 20   // epilogue float row stride (80 B, 16B-aligned)
#define QK_SCALE_LOG2E 0.1803368801111244f   // 0.125 * log2(e)

__global__ __launch_bounds__(256) void attn_mfma(
    const short* __restrict__ qkv, const short* __restrict__ vT,
    _Float16* __restrict__ attn)
{
    // single pool: main loop = Ks[2][64*ASTR] + Vt[2][64*ASTR] shorts (36864 B);
    // epilogue reuses it as float [4][64][RSTR] (20480 B).
    __shared__ __align__(16) char smem[2 * 64 * ASTR * 2 * 2];
    short* KsBuf = (short*)smem;
    short* VtBuf = KsBuf + 2 * 64 * ASTR;

    const int tid  = threadIdx.x;
    const int lane = tid & 63;
    const int wave = tid >> 6;
    const int quad = lane >> 4;
    const int lr   = lane & 15;
    const int qhalf  = wave >> 1;        // which 32-q half this wave owns
    const int cthalf = wave & 1;         // which ct pair this wave owns

    const int bid = blockIdx.x;
    const int qt = bid & 31;             // 32 q-tiles of 64
    const int h  = (bid >> 5) & 15;
    const int b  = bid >> 9;
    const int q0 = qt * 64;

    const short* qbase = qkv + (size_t)b * SLEN * (3 * DMODEL) + h * HDIM;
    const short* kbase = qbase + DMODEL;
    const short* vtbase = vT + (size_t)(b * NHEAD + h) * HDIM * SLEN;

    // 2 q-subtiles as 16x16x32 B-frags, pre-scaled:
    // qf[qs][ds2][j] = Q[q0 + qhalf*32 + qs*16 + lr][ds2*32 + quad*8 + j]
    bf16x8 qf[2][2];
#pragma unroll
    for (int qs = 0; qs < 2; qs++)
#pragma unroll
        for (int ds2 = 0; ds2 < 2; ds2++) {
            bf16x8 q = *(const bf16x8*)&qbase[(size_t)(q0 + qhalf * 32 + qs * 16 + lr) * (3 * DMODEL) + ds2 * 32 + quad * 8];
#pragma unroll
            for (int j = 0; j < 8; j++)
                q[j] = f2bf(bf2f(q[j]) * QK_SCALE_LOG2E);
            qf[qs][ds2] = q;
        }

    // ones A-fragment for the row-sum MFMA (x16 shape)
    bf16x4 ones;
#pragma unroll
    for (int j = 0; j < 4; j++) ones[j] = (short)0x3F80;

    f32x4 oacc[2][4];   // [qs][dt]: O^T partial over this wave's keys
#pragma unroll
    for (int qs = 0; qs < 2; qs++)
#pragma unroll
        for (int t = 0; t < 4; t++) oacc[qs][t] = (f32x4){0.f, 0.f, 0.f, 0.f};
    f32x4 sacc[2] = {{0.f, 0.f, 0.f, 0.f}, {0.f, 0.f, 0.f, 0.f}};

    const int srow = tid >> 3, sc8 = tid & 7;

    // pointer-bumped staging addresses (all 4 waves stage the full tile)
    const short* kp0 = kbase + (size_t)srow * (3 * DMODEL) + sc8 * 8;
    const short* kp1 = kp0 + 32 * (3 * DMODEL);
    const short* vp0 = vtbase + (size_t)srow * SLEN + sc8 * 8;
    const short* vp1 = vp0 + 32 * SLEN;

    bf16x8 kpre[2], vpre[2];
    kpre[0] = *(const bf16x8*)kp0; kpre[1] = *(const bf16x8*)kp1;
    vpre[0] = *(const bf16x8*)vp0; vpre[1] = *(const bf16x8*)vp1;
    kp0 += 64 * (3 * DMODEL); kp1 += 64 * (3 * DMODEL);
    vp0 += 64; vp1 += 64;

    for (int kt = 0; kt < NT; kt++) {
        const int cur = kt & 1;
        short* ks = KsBuf + cur * 64 * ASTR;
        short* vt = VtBuf + cur * 64 * ASTR;

        // write tile kt (in regs) to LDS buffer `cur`
        *(bf16x8*)&ks[srow * ASTR + sc8 * 8] = kpre[0];
        *(bf16x8*)&ks[(srow + 32) * ASTR + sc8 * 8] = kpre[1];
        *(bf16x8*)&vt[srow * ASTR + sc8 * 8] = vpre[0];
        *(bf16x8*)&vt[(srow + 32) * ASTR + sc8 * 8] = vpre[1];

        // issue global loads for tile kt+1
        if (kt + 1 < NT) {
            kpre[0] = *(const bf16x8*)kp0; kpre[1] = *(const bf16x8*)kp1;
            vpre[0] = *(const bf16x8*)vp0; vpre[1] = *(const bf16x8*)vp1;
            kp0 += 64 * (3 * DMODEL); kp1 += 64 * (3 * DMODEL);
            vp0 += 64; vp1 += 64;
        }

        __syncthreads();   // buffer `cur` complete; reads of 1-cur done pre-barrier

        // this wave's 2 key sub-tiles x 2 q-subtiles (4 chains/kt)
#pragma unroll
        for (int ct2 = 0; ct2 < 2; ct2++) {
            const int ct = cthalf * 2 + ct2;
            bf16x8 kf0 = *(const bf16x8*)&ks[(ct * 16 + lr) * ASTR + quad * 8];
            bf16x8 kf1 = *(const bf16x8*)&ks[(ct * 16 + lr) * ASTR + 32 + quad * 8];
            bf16x4 vf0 = *(const bf16x4*)&vt[(0 * 16 + lr) * ASTR + ct * 16 + quad * 4];
            bf16x4 vf1 = *(const bf16x4*)&vt[(1 * 16 + lr) * ASTR + ct * 16 + quad * 4];
            bf16x4 vf2 = *(const bf16x4*)&vt[(2 * 16 + lr) * ASTR + ct * 16 + quad * 4];
            bf16x4 vf3 = *(const bf16x4*)&vt[(3 * 16 + lr) * ASTR + ct * 16 + quad * 4];

#pragma unroll
            for (int qs = 0; qs < 2; qs++) {
                f32x4 st = {0.f, 0.f, 0.f, 0.f};
                st = __builtin_amdgcn_mfma_f32_16x16x32_bf16(kf0, qf[qs][0], st, 0, 0, 0);
                st = __builtin_amdgcn_mfma_f32_16x16x32_bf16(kf1, qf[qs][1], st, 0, 0, 0);

                float p0[4];
#pragma unroll
                for (int r = 0; r < 4; r++) p0[r] = hw_exp2(st[r]);
                union { uint2 u; bf16x4 v; } pk0;
                pk0.u.x = __builtin_amdgcn_perm(fbits(p0[1]), fbits(p0[0]), 0x07060302u);
                pk0.u.y = __builtin_amdgcn_perm(fbits(p0[3]), fbits(p0[2]), 0x07060302u);
                bf16x4 pf0 = pk0.v;

                sacc[qs] = __builtin_amdgcn_mfma_f32_16x16x16bf16_1k(ones, pf0, sacc[qs], 0, 0, 0);
                oacc[qs][0] = __builtin_amdgcn_mfma_f32_16x16x16bf16_1k(vf0, pf0, oacc[qs][0], 0, 0, 0);
                oacc[qs][1] = __builtin_amdgcn_mfma_f32_16x16x16bf16_1k(vf1, pf0, oacc[qs][1], 0, 0, 0);
                oacc[qs][2] = __builtin_amdgcn_mfma_f32_16x16x16bf16_1k(vf2, pf0, oacc[qs][2], 0, 0, 0);
                oacc[qs][3] = __builtin_amdgcn_mfma_f32_16x16x16bf16_1k(vf3, pf0, oacc[qs][3], 0, 0, 0);
            }
        }
    }

    // ---- epilogue: pair (wave, wave^1) shares qhalf; reduce over cthalf.
    __syncthreads();                       // all main-loop LDS reads done
    float* Lf = (float*)smem;              // [4 waves][64 lanes][RSTR]
    float* myrow = Lf + (wave * 64 + lane) * RSTR;

    // round 0 stage (cthalf==1)
    if (cthalf == 1) {
        *(f32x4*)&myrow[0]  = oacc[0][0];
        *(f32x4*)&myrow[4]  = oacc[0][1];
        *(f32x4*)&myrow[8]  = oacc[0][2];
        *(f32x4*)&myrow[12] = oacc[0][3];
        myrow[16] = sacc[0][0];
    }
    __syncthreads();
    if (cthalf == 0) {
        // finalize qs=0
        const float* pr = Lf + ((wave ^ 1) * 64 + lane) * RSTR;
        f32x4 o0 = oacc[0][0] + *(const f32x4*)&pr[0];
        f32x4 o1 = oacc[0][1] + *(const f32x4*)&pr[4];
        f32x4 o2 = oacc[0][2] + *(const f32x4*)&pr[8];
        f32x4 o3 = oacc[0][3] + *(const f32x4*)&pr[12];
        const float inv = 1.0f / (sacc[0][0] + pr[16]);
        const int row = b * SLEN + q0 + qhalf * 32 + lr;
        f16x4 h4;
#pragma unroll
        for (int r = 0; r < 4; r++) h4[r] = (_Float16)(o0[r] * inv);
        *(f16x4*)&attn[(size_t)row * DMODEL + h * HDIM + 0 * 16 + quad * 4] = h4;
#pragma unroll
        for (int r = 0; r < 4; r++) h4[r] = (_Float16)(o1[r] * inv);
        *(f16x4*)&attn[(size_t)row * DMODEL + h * HDIM + 1 * 16 + quad * 4] = h4;
#pragma unroll
        for (int r = 0; r < 4; r++) h4[r] = (_Float16)(o2[r] * inv);
        *(f16x4*)&attn[(size_t)row * DMODEL + h * HDIM + 2 * 16 + quad * 4] = h4;
#pragma unroll
        for (int r = 0; r < 4; r++) h4[r] = (_Float16)(o3[r] * inv);
        *(f16x4*)&attn[(size_t)row * DMODEL + h * HDIM + 3 * 16 + quad * 4] = h4;
        // round 1 stage (cthalf==0)
        *(f32x4*)&myrow[0]  = oacc[1][0];
        *(f32x4*)&myrow[4]  = oacc[1][1];
        *(f32x4*)&myrow[8]  = oacc[1][2];
        *(f32x4*)&myrow[12] = oacc[1][3];
        myrow[16] = sacc[1][0];
    }
    __syncthreads();
    if (cthalf == 1) {
        // finalize qs=1
        const float* pr = Lf + ((wave ^ 1) * 64 + lane) * RSTR;
        f32x4 o0 = oacc[1][0] + *(const f32x4*)&pr[0];
        f32x4 o1 = oacc[1][1] + *(const f32x4*)&pr[4];
        f32x4 o2 = oacc[1][2] + *(const f32x4*)&pr[8];
        f32x4 o3 = oacc[1][3] + *(const f32x4*)&pr[12];
        const float inv = 1.0f / (sacc[1][0] + pr[16]);
        const int row = b * SLEN + q0 + qhalf * 32 + 16 + lr;
        f16x4 h4;
#pragma unroll
        for (int r = 0; r < 4; r++) h4[r] = (_Float16)(o0[r] * inv);
        *(f16x4*)&attn[(size_t)row * DMODEL + h * HDIM + 0 * 16 + quad * 4] = h4;
#pragma unroll
        for (int r = 0; r < 4; r++) h4[r] = (_Float16)(o1[r] * inv);
        *(f16x4*)&attn[(size_t)row * DMODEL + h * HDIM + 1 * 16 + quad * 4] = h4;
#pragma unroll
        for (int r = 0; r < 4; r++) h4[r] = (_Float16)(o2[r] * inv);
        *(f16x4*)&attn[(size_t)row * DMODEL + h * HDIM + 2 * 16 + quad * 4] = h4;
#pragma unroll
        for (int r = 0; r < 4; r++) h4[r] = (_Float16)(o3[r] * inv);
        *(f16x4*)&attn[(size_t)row * DMODEL + h * HDIM + 3 * 16 + quad * 4] = h4;
    }
}

extern "C" void kernel_launch(void* const* d_in, const int* in_sizes, int n_in,
                              void* d_out, int out_size, void* d_ws, size_t ws_size,
                              hipStream_t stream) {
    (void)in_sizes; (void)n_in; (void)out_size; (void)ws_size;
    const float* x     = (const float*)d_in[0];
    const float* Wqkv  = (const float*)d_in[1];
    const float* bqkv  = (const float*)d_in[2];
    const float* Wproj = (const float*)d_in[3];
    const float* bproj = (const float*)d_in[4];
    float* out = (float*)d_out;

    // workspace layout (2-byte units), peak ~58.6 MB
    short* qkv = (short*)d_ws;                               // 4096*3072 bf16
    _Float16* xf = (_Float16*)(qkv + (size_t)MROWS * 3 * DMODEL);  // 4096*1024 f16
    _Float16* wq = xf + (size_t)MROWS * DMODEL;              // 3072*1024 f16 (W_qkv^T)
    _Float16* wp = wq + (size_t)3 * DMODEL * DMODEL;         // 1024*1024 f16 (W_proj^T)
    short* vT = (short*)(wp + (size_t)DMODEL * DMODEL);      // 4096*1024 bf16
    _Float16* attnb = (_Float16*)(vT + (size_t)MROWS * DMODEL); // 4096*1024 f16

    // 0) fused prep: cast x; transpose both weights (one launch)
    prep<<<dim3(NCAST + NTW1 + NTW2), 256, 0, stream>>>(x, xf, Wqkv, wq, Wproj, wp);

    // 1) qkv(bf16) = x @ W_qkv + b_qkv   (fp16 MFMA, BK=64, global_load_lds)
    gemm_f16<1><<<dim3(3 * DMODEL / 128, MROWS / 128), 256, 0, stream>>>(
        xf, wq, bqkv, (void*)qkv, MROWS, 3 * DMODEL, DMODEL);

    // 1b) transpose V section -> vT[b][h][d][s]
    transpose_v<<<dim3(BATCH * NHEAD * (SLEN / 64)), 256, 0, stream>>>(qkv, vT);

    // 2) fused attention: bf16 qkv + vT -> attn (fp16); 64 q-rows/block,
    //    per-wave q/ct split + pair reduce
    attn_mfma<<<dim3(BATCH * NHEAD * (SLEN / 64)), 256, 0, stream>>>(qkv, vT, attnb);

    // 3) out(fp32) = attn @ W_proj + b_proj   (fp16 MFMA, BK=64, global_load_lds)
    gemm_f16<0><<<dim3(DMODEL / 128, MROWS / 128), 256, 0, stream>>>(
        attnb, wp, bproj, (void*)out, MROWS, DMODEL, DMODEL);
}

// Round 12
// 197.704 us; speedup vs baseline: 1.0643x; 1.0643x over previous
//
#include <hip/hip_runtime.h>

// Problem constants
#define BATCH 2
#define SLEN 2048
#define DMODEL 1024
#define NHEAD 16
#define HDIM 64
#define MROWS (BATCH * SLEN)   // 4096

typedef __attribute__((ext_vector_type(8))) short bf16x8;
typedef __attribute__((ext_vector_type(4))) short bf16x4;
typedef __attribute__((ext_vector_type(4))) float f32x4;
typedef __attribute__((ext_vector_type(8))) _Float16 f16x8;
typedef __attribute__((ext_vector_type(4))) _Float16 f16x4;

__device__ inline short f2bf(float x) {
    union { float f; unsigned u; } v; v.f = x;
    unsigned r = (v.u + 0x7FFFu + ((v.u >> 16) & 1u)) >> 16;
    return (short)r;
}
__device__ inline float bf2f(short h) {
    union { unsigned u; float f; } v; v.u = ((unsigned)(unsigned short)h) << 16;
    return v.f;
}
__device__ inline unsigned fbits(float x) {
    union { float f; unsigned u; } v; v.f = x; return v.u;
}
// raw hardware exp2: one v_exp_f32 (args bounded; no denormal fixup needed)
__device__ inline float hw_exp2(float x) {
    float r;
    asm("v_exp_f32 %0, %1" : "=v"(r) : "v"(x));
    return r;
}

// ---------------- fused prep: cast x -> fp16  +  transpose both weight
// matrices to fp16 [N][K]. One launch instead of three.
#define NCAST (MROWS * DMODEL / 4 / 256)                    // 4096 blocks
#define NTW1  ((3 * DMODEL / 64) * (DMODEL / 64))           // 48*16 = 768
#define NTW2  ((DMODEL / 64) * (DMODEL / 64))               // 16*16 = 256

__global__ __launch_bounds__(256) void prep(
    const float* __restrict__ x, _Float16* __restrict__ xf,
    const float* __restrict__ Wqkv, _Float16* __restrict__ wq,
    const float* __restrict__ Wproj, _Float16* __restrict__ wp)
{
    __shared__ float T[64][68];
    int bid = blockIdx.x;
    const int tid = threadIdx.x;

    if (bid < NCAST) {            // ---- cast x (uniform per block; no barrier)
        int i = bid * 256 + tid;
        float4 f = ((const float4*)x)[i];
        f16x4 h;
        h[0] = (_Float16)f.x; h[1] = (_Float16)f.y;
        h[2] = (_Float16)f.z; h[3] = (_Float16)f.w;
        ((f16x4*)xf)[i] = h;
        return;
    }
    bid -= NCAST;

    const float* in; _Float16* outT; int N; int n0, k0;
    if (bid < NTW1) {             // ---- transpose W_qkv [1024][3072]
        in = Wqkv; outT = wq; N = 3 * DMODEL;
        n0 = (bid % 48) * 64; k0 = (bid / 48) * 64;
    } else {                      // ---- transpose W_proj [1024][1024]
        bid -= NTW1;
        in = Wproj; outT = wp; N = DMODEL;
        n0 = (bid % 16) * 64; k0 = (bid / 16) * 64;
    }
    const int K = DMODEL;

#pragma unroll
    for (int i = 0; i < 4; i++) {
        int idx = tid + i * 256;
        int r = idx >> 4, c4 = idx & 15;
        *(float4*)&T[r][c4 * 4] = *(const float4*)&in[(size_t)(k0 + r) * N + n0 + c4 * 4];
    }
    __syncthreads();
#pragma unroll
    for (int i = 0; i < 4; i++) {
        int idx = tid + i * 256;
        int n = idx >> 4, kg = idx & 15;
        f16x4 h;
#pragma unroll
        for (int j = 0; j < 4; j++)
            h[j] = (_Float16)T[kg * 4 + j][n];
        *(f16x4*)&outT[(size_t)(n0 + n) * K + k0 + kg * 4] = h;
    }
}

// ---------------- transpose V section of qkv -> vT[b][h][d][s]  (bf16)
__global__ __launch_bounds__(256) void transpose_v(
    const short* __restrict__ qkv, short* __restrict__ vT)
{
    __shared__ short T[64 * 68];   // [s][d], stride 68 shorts
    const int tid = threadIdx.x;
    const int bid = blockIdx.x;
    const int st = bid & 31, h = (bid >> 5) & 15, b = bid >> 9;
    const int s0 = st * 64;
    const short* src = qkv + (size_t)b * SLEN * (3 * DMODEL) + 2 * DMODEL + h * HDIM;

    const int srow = tid >> 3, sc8 = tid & 7;
#pragma unroll
    for (int it = 0; it < 2; it++) {
        int s = srow + it * 32;
        *(bf16x8*)&T[s * 68 + sc8 * 8] =
            *(const bf16x8*)&src[(size_t)(s0 + s) * (3 * DMODEL) + sc8 * 8];
    }
    __syncthreads();

    const int d = tid >> 2, sq = tid & 3;
    short* dst = vT + ((size_t)(b * NHEAD + h) * HDIM + d) * SLEN + s0 + sq * 16;
    bf16x8 o0, o1;
#pragma unroll
    for (int j = 0; j < 8; j++) {
        o0[j] = T[(sq * 16 + j) * 68 + d];
        o1[j] = T[(sq * 16 + 8 + j) * 68 + d];
    }
    *(bf16x8*)&dst[0] = o0;
    *(bf16x8*)&dst[8] = o1;
}

// ---------------- plain fp16 MFMA GEMM: C = A[M,K] · B[K,N] + bias
// B given TRANSPOSED [N][K] fp16. BM x 128 tiles, BK=64, 2-phase register
// prefetch (v17 — best measured; v18's global_load_lds single-buffer dropped
// the prefetch overlap and regressed 18 µs: technique without its
// prerequisite). BM=128 for the qkv GEMM; BM=64 for the proj GEMM so its
// grid is 512 blocks (2 blocks/CU) instead of 256 (1/CU, 1 wave/SIMD).
#define GSTR2 72   // LDS row stride (f16): 144 B; read bank-starts {0,4..28} = free 2-way

template<int OUT_BF16, int BM>
__global__ __launch_bounds__(256) void gemm_f16(
    const _Float16* __restrict__ A, const _Float16* __restrict__ Bw,
    const float* __restrict__ bias, void* __restrict__ Cout,
    int M, int N, int K)
{
    // A-tile: BM x 64, B-tile: 128 x 64
    __shared__ _Float16 As[BM * GSTR2], Bs[128 * GSTR2];

    const int tid  = threadIdx.x;
    const int wave = tid >> 6, lane = tid & 63;
    const int quad = lane >> 4, lr = lane & 15;
    // BM=128: waves 2x2, each 64x64 (acc 4x4). BM=64: each 32x64 (acc 2x4).
    constexpr int MT = (BM == 128) ? 4 : 2;
    const int wm = (wave >> 1) * (BM / 2), wn = (wave & 1) * 64;
    const int row0 = blockIdx.y * BM, col0 = blockIdx.x * 128;

    f32x4 acc[MT][4];
#pragma unroll
    for (int i = 0; i < MT; i++)
#pragma unroll
        for (int j = 0; j < 4; j++) acc[i][j] = (f32x4){0.f, 0.f, 0.f, 0.f};

    const int sr = tid >> 2, sc = tid & 3;

    // staging pointers: A rows sr (+64 if BM=128), B rows sr / sr+64
    const _Float16* ap0 = A  + (size_t)(row0 + sr) * K + sc * 8;
    const _Float16* ap1 = ap0 + (size_t)64 * K;     // used only when BM=128
    const _Float16* bp0 = Bw + (size_t)(col0 + sr) * K + sc * 8;
    const _Float16* bp1 = bp0 + (size_t)64 * K;

    f16x8 apre[4], bpre[4];
    apre[0] = *(const f16x8*)ap0;        apre[1] = *(const f16x8*)(ap0 + 32);
    if (BM == 128) { apre[2] = *(const f16x8*)ap1; apre[3] = *(const f16x8*)(ap1 + 32); }
    bpre[0] = *(const f16x8*)bp0;        bpre[1] = *(const f16x8*)(bp0 + 32);
    bpre[2] = *(const f16x8*)bp1;        bpre[3] = *(const f16x8*)(bp1 + 32);
    ap0 += 64; ap1 += 64; bp0 += 64; bp1 += 64;

    const int ls = sr * GSTR2 + sc * 8;

    for (int k0 = 0; k0 < K; k0 += 64) {
        // write prefetched tiles to LDS (prev reads done: trailing barrier)
        *(f16x8*)&As[ls]                    = apre[0];
        *(f16x8*)&As[ls + 32]               = apre[1];
        if (BM == 128) {
            *(f16x8*)&As[ls + 64 * GSTR2]       = apre[2];
            *(f16x8*)&As[ls + 64 * GSTR2 + 32]  = apre[3];
        }
        *(f16x8*)&Bs[ls]                    = bpre[0];
        *(f16x8*)&Bs[ls + 32]               = bpre[1];
        *(f16x8*)&Bs[ls + 64 * GSTR2]       = bpre[2];
        *(f16x8*)&Bs[ls + 64 * GSTR2 + 32]  = bpre[3];

        // issue global loads for tile k0+64 (hidden under this tile's compute)
        if (k0 + 64 < K) {
            apre[0] = *(const f16x8*)ap0;        apre[1] = *(const f16x8*)(ap0 + 32);
            if (BM == 128) { apre[2] = *(const f16x8*)ap1; apre[3] = *(const f16x8*)(ap1 + 32); }
            bpre[0] = *(const f16x8*)bp0;        bpre[1] = *(const f16x8*)(bp0 + 32);
            bpre[2] = *(const f16x8*)bp1;        bpre[3] = *(const f16x8*)(bp1 + 32);
            ap0 += 64; ap1 += 64; bp0 += 64; bp1 += 64;
        }

        __syncthreads();

#pragma unroll
        for (int kk = 0; kk < 2; kk++) {
            f16x8 af[MT];
#pragma unroll
            for (int mt = 0; mt < MT; mt++)
                af[mt] = *(const f16x8*)&As[(wm + mt * 16 + lr) * GSTR2 + kk * 32 + quad * 8];
#pragma unroll
            for (int nt = 0; nt < 4; nt++) {
                f16x8 b = *(const f16x8*)&Bs[(wn + nt * 16 + lr) * GSTR2 + kk * 32 + quad * 8];
#pragma unroll
                for (int mt = 0; mt < MT; mt++)
                    acc[mt][nt] = __builtin_amdgcn_mfma_f32_16x16x32_f16(af[mt], b, acc[mt][nt], 0, 0, 0);
            }
        }

        __syncthreads();   // reads done; next iter may overwrite LDS
    }

    // epilogue: D[m = quad*4 + r][n = lr]
#pragma unroll
    for (int mt = 0; mt < MT; mt++) {
#pragma unroll
        for (int nt = 0; nt < 4; nt++) {
            int col = col0 + wn + nt * 16 + lr;
            float bv = bias[col];
#pragma unroll
            for (int r = 0; r < 4; r++) {
                int row = row0 + wm + mt * 16 + quad * 4 + r;
                float v = acc[mt][nt][r] + bv;
                if (OUT_BF16)
                    ((short*)Cout)[(size_t)row * N + col] = f2bf(v);
                else
                    ((float*)Cout)[(size_t)row * N + col] = v;
            }
        }
    }
}

// ---------------- fused attention v16 (verified 65.5 µs): q/ct split per
// wave + pair-reduce epilogue. NOTE: plain __launch_bounds__(256) — the
// (256,4) min-occupancy cap produced silently-wrong spill codegen twice
// (v10, v15). Keep plain.
#define ASTR 72   // LDS row stride (shorts): 144 B, 16B-aligned rows
#define NT   (SLEN / 64)
#define RSTR 20   // epilogue float row stride (80 B, 16B-aligned)
#define QK_SCALE_LOG2E 0.1803368801111244f   // 0.125 * log2(e)

__global__ __launch_bounds__(256) void attn_mfma(
    const short* __restrict__ qkv, const short* __restrict__ vT,
    _Float16* __restrict__ attn)
{
    // single pool: main loop = Ks[2][64*ASTR] + Vt[2][64*ASTR] shorts (36864 B);
    // epilogue reuses it as float [4][64][RSTR] (20480 B).
    __shared__ __align__(16) char smem[2 * 64 * ASTR * 2 * 2];
    short* KsBuf = (short*)smem;
    short* VtBuf = KsBuf + 2 * 64 * ASTR;

    const int tid  = threadIdx.x;
    const int lane = tid & 63;
    const int wave = tid >> 6;
    const int quad = lane >> 4;
    const int lr   = lane & 15;
    const int qhalf  = wave >> 1;        // which 32-q half this wave owns
    const int cthalf = wave & 1;         // which ct pair this wave owns

    const int bid = blockIdx.x;
    const int qt = bid & 31;             // 32 q-tiles of 64
    const int h  = (bid >> 5) & 15;
    const int b  = bid >> 9;
    const int q0 = qt * 64;

    const short* qbase = qkv + (size_t)b * SLEN * (3 * DMODEL) + h * HDIM;
    const short* kbase = qbase + DMODEL;
    const short* vtbase = vT + (size_t)(b * NHEAD + h) * HDIM * SLEN;

    // 2 q-subtiles as 16x16x32 B-frags, pre-scaled:
    // qf[qs][ds2][j] = Q[q0 + qhalf*32 + qs*16 + lr][ds2*32 + quad*8 + j]
    bf16x8 qf[2][2];
#pragma unroll
    for (int qs = 0; qs < 2; qs++)
#pragma unroll
        for (int ds2 = 0; ds2 < 2; ds2++) {
            bf16x8 q = *(const bf16x8*)&qbase[(size_t)(q0 + qhalf * 32 + qs * 16 + lr) * (3 * DMODEL) + ds2 * 32 + quad * 8];
#pragma unroll
            for (int j = 0; j < 8; j++)
                q[j] = f2bf(bf2f(q[j]) * QK_SCALE_LOG2E);
            qf[qs][ds2] = q;
        }

    // ones A-fragment for the row-sum MFMA (x16 shape)
    bf16x4 ones;
#pragma unroll
    for (int j = 0; j < 4; j++) ones[j] = (short)0x3F80;

    f32x4 oacc[2][4];   // [qs][dt]: O^T partial over this wave's keys
#pragma unroll
    for (int qs = 0; qs < 2; qs++)
#pragma unroll
        for (int t = 0; t < 4; t++) oacc[qs][t] = (f32x4){0.f, 0.f, 0.f, 0.f};
    f32x4 sacc[2] = {{0.f, 0.f, 0.f, 0.f}, {0.f, 0.f, 0.f, 0.f}};

    const int srow = tid >> 3, sc8 = tid & 7;

    // pointer-bumped staging addresses (all 4 waves stage the full tile)
    const short* kp0 = kbase + (size_t)srow * (3 * DMODEL) + sc8 * 8;
    const short* kp1 = kp0 + 32 * (3 * DMODEL);
    const short* vp0 = vtbase + (size_t)srow * SLEN + sc8 * 8;
    const short* vp1 = vp0 + 32 * SLEN;

    bf16x8 kpre[2], vpre[2];
    kpre[0] = *(const bf16x8*)kp0; kpre[1] = *(const bf16x8*)kp1;
    vpre[0] = *(const bf16x8*)vp0; vpre[1] = *(const bf16x8*)vp1;
    kp0 += 64 * (3 * DMODEL); kp1 += 64 * (3 * DMODEL);
    vp0 += 64; vp1 += 64;

    for (int kt = 0; kt < NT; kt++) {
        const int cur = kt & 1;
        short* ks = KsBuf + cur * 64 * ASTR;
        short* vt = VtBuf + cur * 64 * ASTR;

        // write tile kt (in regs) to LDS buffer `cur`
        *(bf16x8*)&ks[srow * ASTR + sc8 * 8] = kpre[0];
        *(bf16x8*)&ks[(srow + 32) * ASTR + sc8 * 8] = kpre[1];
        *(bf16x8*)&vt[srow * ASTR + sc8 * 8] = vpre[0];
        *(bf16x8*)&vt[(srow + 32) * ASTR + sc8 * 8] = vpre[1];

        // issue global loads for tile kt+1
        if (kt + 1 < NT) {
            kpre[0] = *(const bf16x8*)kp0; kpre[1] = *(const bf16x8*)kp1;
            vpre[0] = *(const bf16x8*)vp0; vpre[1] = *(const bf16x8*)vp1;
            kp0 += 64 * (3 * DMODEL); kp1 += 64 * (3 * DMODEL);
            vp0 += 64; vp1 += 64;
        }

        __syncthreads();   // buffer `cur` complete; reads of 1-cur done pre-barrier

        // this wave's 2 key sub-tiles x 2 q-subtiles (4 chains/kt)
#pragma unroll
        for (int ct2 = 0; ct2 < 2; ct2++) {
            const int ct = cthalf * 2 + ct2;
            bf16x8 kf0 = *(const bf16x8*)&ks[(ct * 16 + lr) * ASTR + quad * 8];
            bf16x8 kf1 = *(const bf16x8*)&ks[(ct * 16 + lr) * ASTR + 32 + quad * 8];
            bf16x4 vf0 = *(const bf16x4*)&vt[(0 * 16 + lr) * ASTR + ct * 16 + quad * 4];
            bf16x4 vf1 = *(const bf16x4*)&vt[(1 * 16 + lr) * ASTR + ct * 16 + quad * 4];
            bf16x4 vf2 = *(const bf16x4*)&vt[(2 * 16 + lr) * ASTR + ct * 16 + quad * 4];
            bf16x4 vf3 = *(const bf16x4*)&vt[(3 * 16 + lr) * ASTR + ct * 16 + quad * 4];

#pragma unroll
            for (int qs = 0; qs < 2; qs++) {
                f32x4 st = {0.f, 0.f, 0.f, 0.f};
                st = __builtin_amdgcn_mfma_f32_16x16x32_bf16(kf0, qf[qs][0], st, 0, 0, 0);
                st = __builtin_amdgcn_mfma_f32_16x16x32_bf16(kf1, qf[qs][1], st, 0, 0, 0);

                float p0[4];
#pragma unroll
                for (int r = 0; r < 4; r++) p0[r] = hw_exp2(st[r]);
                union { uint2 u; bf16x4 v; } pk0;
                pk0.u.x = __builtin_amdgcn_perm(fbits(p0[1]), fbits(p0[0]), 0x07060302u);
                pk0.u.y = __builtin_amdgcn_perm(fbits(p0[3]), fbits(p0[2]), 0x07060302u);
                bf16x4 pf0 = pk0.v;

                sacc[qs] = __builtin_amdgcn_mfma_f32_16x16x16bf16_1k(ones, pf0, sacc[qs], 0, 0, 0);
                oacc[qs][0] = __builtin_amdgcn_mfma_f32_16x16x16bf16_1k(vf0, pf0, oacc[qs][0], 0, 0, 0);
                oacc[qs][1] = __builtin_amdgcn_mfma_f32_16x16x16bf16_1k(vf1, pf0, oacc[qs][1], 0, 0, 0);
                oacc[qs][2] = __builtin_amdgcn_mfma_f32_16x16x16bf16_1k(vf2, pf0, oacc[qs][2], 0, 0, 0);
                oacc[qs][3] = __builtin_amdgcn_mfma_f32_16x16x16bf16_1k(vf3, pf0, oacc[qs][3], 0, 0, 0);
            }
        }
    }

    // ---- epilogue: pair (wave, wave^1) shares qhalf; reduce over cthalf.
    __syncthreads();                       // all main-loop LDS reads done
    float* Lf = (float*)smem;              // [4 waves][64 lanes][RSTR]
    float* myrow = Lf + (wave * 64 + lane) * RSTR;

    // round 0 stage (cthalf==1)
    if (cthalf == 1) {
        *(f32x4*)&myrow[0]  = oacc[0][0];
        *(f32x4*)&myrow[4]  = oacc[0][1];
        *(f32x4*)&myrow[8]  = oacc[0][2];
        *(f32x4*)&myrow[12] = oacc[0][3];
        myrow[16] = sacc[0][0];
    }
    __syncthreads();
    if (cthalf == 0) {
        // finalize qs=0
        const float* pr = Lf + ((wave ^ 1) * 64 + lane) * RSTR;
        f32x4 o0 = oacc[0][0] + *(const f32x4*)&pr[0];
        f32x4 o1 = oacc[0][1] + *(const f32x4*)&pr[4];
        f32x4 o2 = oacc[0][2] + *(const f32x4*)&pr[8];
        f32x4 o3 = oacc[0][3] + *(const f32x4*)&pr[12];
        const float inv = 1.0f / (sacc[0][0] + pr[16]);
        const int row = b * SLEN + q0 + qhalf * 32 + lr;
        f16x4 h4;
#pragma unroll
        for (int r = 0; r < 4; r++) h4[r] = (_Float16)(o0[r] * inv);
        *(f16x4*)&attn[(size_t)row * DMODEL + h * HDIM + 0 * 16 + quad * 4] = h4;
#pragma unroll
        for (int r = 0; r < 4; r++) h4[r] = (_Float16)(o1[r] * inv);
        *(f16x4*)&attn[(size_t)row * DMODEL + h * HDIM + 1 * 16 + quad * 4] = h4;
#pragma unroll
        for (int r = 0; r < 4; r++) h4[r] = (_Float16)(o2[r] * inv);
        *(f16x4*)&attn[(size_t)row * DMODEL + h * HDIM + 2 * 16 + quad * 4] = h4;
#pragma unroll
        for (int r = 0; r < 4; r++) h4[r] = (_Float16)(o3[r] * inv);
        *(f16x4*)&attn[(size_t)row * DMODEL + h * HDIM + 3 * 16 + quad * 4] = h4;
        // round 1 stage (cthalf==0)
        *(f32x4*)&myrow[0]  = oacc[1][0];
        *(f32x4*)&myrow[4]  = oacc[1][1];
        *(f32x4*)&myrow[8]  = oacc[1][2];
        *(f32x4*)&myrow[12] = oacc[1][3];
        myrow[16] = sacc[1][0];
    }
    __syncthreads();
    if (cthalf == 1) {
        // finalize qs=1
        const float* pr = Lf + ((wave ^ 1) * 64 + lane) * RSTR;
        f32x4 o0 = oacc[1][0] + *(const f32x4*)&pr[0];
        f32x4 o1 = oacc[1][1] + *(const f32x4*)&pr[4];
        f32x4 o2 = oacc[1][2] + *(const f32x4*)&pr[8];
        f32x4 o3 = oacc[1][3] + *(const f32x4*)&pr[12];
        const float inv = 1.0f / (sacc[1][0] + pr[16]);
        const int row = b * SLEN + q0 + qhalf * 32 + 16 + lr;
        f16x4 h4;
#pragma unroll
        for (int r = 0; r < 4; r++) h4[r] = (_Float16)(o0[r] * inv);
        *(f16x4*)&attn[(size_t)row * DMODEL + h * HDIM + 0 * 16 + quad * 4] = h4;
#pragma unroll
        for (int r = 0; r < 4; r++) h4[r] = (_Float16)(o1[r] * inv);
        *(f16x4*)&attn[(size_t)row * DMODEL + h * HDIM + 1 * 16 + quad * 4] = h4;
#pragma unroll
        for (int r = 0; r < 4; r++) h4[r] = (_Float16)(o2[r] * inv);
        *(f16x4*)&attn[(size_t)row * DMODEL + h * HDIM + 2 * 16 + quad * 4] = h4;
#pragma unroll
        for (int r = 0; r < 4; r++) h4[r] = (_Float16)(o3[r] * inv);
        *(f16x4*)&attn[(size_t)row * DMODEL + h * HDIM + 3 * 16 + quad * 4] = h4;
    }
}

extern "C" void kernel_launch(void* const* d_in, const int* in_sizes, int n_in,
                              void* d_out, int out_size, void* d_ws, size_t ws_size,
                              hipStream_t stream) {
    (void)in_sizes; (void)n_in; (void)out_size; (void)ws_size;
    const float* x     = (const float*)d_in[0];
    const float* Wqkv  = (const float*)d_in[1];
    const float* bqkv  = (const float*)d_in[2];
    const float* Wproj = (const float*)d_in[3];
    const float* bproj = (const float*)d_in[4];
    float* out = (float*)d_out;

    // workspace layout (2-byte units), peak ~58.6 MB
    short* qkv = (short*)d_ws;                               // 4096*3072 bf16
    _Float16* xf = (_Float16*)(qkv + (size_t)MROWS * 3 * DMODEL);  // 4096*1024 f16
    _Float16* wq = xf + (size_t)MROWS * DMODEL;              // 3072*1024 f16 (W_qkv^T)
    _Float16* wp = wq + (size_t)3 * DMODEL * DMODEL;         // 1024*1024 f16 (W_proj^T)
    short* vT = (short*)(wp + (size_t)DMODEL * DMODEL);      // 4096*1024 bf16
    _Float16* attnb = (_Float16*)(vT + (size_t)MROWS * DMODEL); // 4096*1024 f16

    // 0) fused prep: cast x; transpose both weights (one launch)
    prep<<<dim3(NCAST + NTW1 + NTW2), 256, 0, stream>>>(x, xf, Wqkv, wq, Wproj, wp);

    // 1) qkv(bf16) = x @ W_qkv + b_qkv   (fp16 MFMA, BM=128, BK=64, 2-phase)
    gemm_f16<1, 128><<<dim3(3 * DMODEL / 128, MROWS / 128), 256, 0, stream>>>(
        xf, wq, bqkv, (void*)qkv, MROWS, 3 * DMODEL, DMODEL);

    // 1b) transpose V section -> vT[b][h][d][s]
    transpose_v<<<dim3(BATCH * NHEAD * (SLEN / 64)), 256, 0, stream>>>(qkv, vT);

    // 2) fused attention: bf16 qkv + vT -> attn (fp16); 64 q-rows/block,
    //    per-wave q/ct split + pair reduce
    attn_mfma<<<dim3(BATCH * NHEAD * (SLEN / 64)), 256, 0, stream>>>(qkv, vT, attnb);

    // 3) out(fp32) = attn @ W_proj + b_proj   (fp16 MFMA, BM=64 -> 512 blocks,
    //    2 blocks/CU instead of 1)
    gemm_f16<0, 64><<<dim3(DMODEL / 128, MROWS / 64), 256, 0, stream>>>(
        attnb, wp, bproj, (void*)out, MROWS, DMODEL, DMODEL);
}